// Round 5
// baseline (416.809 us; speedup 1.0000x reference)
//
#include <hip/hip_runtime.h>

#define NB 147456   // C*C*KH*KW per sample
#define ZD 256
#define BSZ 32
#define CCH 128

typedef __attribute__((ext_vector_type(8))) short short8;
typedef __attribute__((ext_vector_type(16))) float floatx16;

__device__ __forceinline__ unsigned short f2bf(float f) {
    unsigned int u = __float_as_uint(f);
    return (unsigned short)((u + 0x7fffu + ((u >> 16) & 1u)) >> 16);
}

// ---- K1: h = relu(z@W+b); BN over batch; affine; -> bf16 Wk natural [b][n] --------------------
// 1 col/thread (9 waves/CU). z reads are wave-uniform -> scalar loads (SMEM pipe, no LDS).
// Weight stream: 16-deep dword prefetch, double-buffered, rolled loop (I-cache friendly).
__global__ __launch_bounds__(256) void hyper_gemm_bn(
    const float* __restrict__ z, const float* __restrict__ dw,
    const float* __restrict__ db, const float* __restrict__ gamma,
    const float* __restrict__ beta, unsigned short* __restrict__ wkn)
{
    int n = blockIdx.x * 256 + threadIdx.x;   // 576 blocks
    float acc[32];
#pragma unroll
    for (int b = 0; b < 32; b++) acc[b] = 0.f;

    float wa[16], wb[16];
#pragma unroll
    for (int j = 0; j < 16; j++) wa[j] = dw[(size_t)j * NB + n];

#define FMA_CHUNK(CC, W)                                              \
    {                                                                 \
        _Pragma("unroll")                                             \
        for (int b = 0; b < 32; b++) {                                \
            _Pragma("unroll")                                         \
            for (int j = 0; j < 16; j++)                              \
                acc[b] += z[b * 256 + (CC) * 16 + j] * W[j];          \
        }                                                             \
    }

    for (int c = 0; c < 16; c += 2) {         // rolled: body = 2 chunks (~1K fmac, fits I-cache)
#pragma unroll
        for (int j = 0; j < 16; j++)
            wb[j] = dw[(size_t)((c + 1) * 16 + j) * NB + n];
        FMA_CHUNK(c, wa)
        if (c + 2 < 16) {
#pragma unroll
            for (int j = 0; j < 16; j++)
                wa[j] = dw[(size_t)((c + 2) * 16 + j) * NB + n];
        }
        FMA_CHUNK(c + 1, wb)
    }
#undef FMA_CHUNK

    float bias = db[n];
    float s0 = 0.f, q0 = 0.f;
#pragma unroll
    for (int b = 0; b < 32; b++) {
        float h = fmaxf(acc[b] + bias, 0.f);
        acc[b] = h;
        s0 += h;
        q0 += h * h;
    }
    float m = s0 * (1.f / 32.f);
    float v = fmaxf(q0 * (1.f / 32.f) - m * m, 0.f);
    float sc = gamma[n] / (sqrtf(v) + 1e-6f);
    float bt = beta[n];
#pragma unroll
    for (int b = 0; b < 32; b++)              // wave-contiguous 128B u16 stores per b (L2 merges)
        wkn[(size_t)b * NB + n] = f2bf(sc * (acc[b] - m) + bt);
}

// ---- fused: blocks 0..255 repack wkn->wkt; blocks 256..1279 transpose x -> xT bf16 -----------
__global__ __launch_bounds__(256) void repack_xt(
    const unsigned short* __restrict__ wkn, unsigned short* __restrict__ wkt,
    const float* __restrict__ x, unsigned short* __restrict__ xb16)
{
    __shared__ char lmem[16 * 580 * 4];       // 37120 B, shared by both roles
    int t = threadIdx.x;
    if (blockIdx.x < 256) {
        // repack: wkn[b][s*1152 + f*9 + uv] -> wkt[b][uv][f][s]
        unsigned int* lt = (unsigned int*)lmem;   // [16][580]
        int b = blockIdx.x >> 3;
        int s0 = (blockIdx.x & 7) * 16;
        const unsigned int* src = (const unsigned int*)wkn + ((size_t)b * NB >> 1) + (size_t)s0 * 576;
#pragma unroll
        for (int i = 0; i < 36; i++) {
            int idx = t + i * 256;
            int si = idx / 576;
            int j2 = idx - si * 576;
            lt[si * 580 + j2] = src[(size_t)si * 576 + j2];
        }
        __syncthreads();
        const unsigned short* ls = (const unsigned short*)lt;
#pragma unroll
        for (int i = 0; i < 9; i++) {
            int tau = t + i * 256;
            int half = tau & 1;
            int unit = tau >> 1;
            int uv = unit >> 7;
            int f = unit & 127;
            int col = f * 9 + uv;
            unsigned short v[8];
#pragma unroll
            for (int ss = 0; ss < 8; ss++)
                v[ss] = ls[(half * 8 + ss) * 1160 + col];
            uint4 o;
            o.x = v[0] | ((unsigned)v[1] << 16);
            o.y = v[2] | ((unsigned)v[3] << 16);
            o.z = v[4] | ((unsigned)v[5] << 16);
            o.w = v[6] | ((unsigned)v[7] << 16);
            ((uint4*)wkt)[((((size_t)b * 9 + uv) * 128 + f) * 16) + (s0 >> 3) + half] = o;
        }
    } else {
        // x transpose: x[b][s][p][q] fp32 -> xT[b][p][q][s] bf16
        unsigned short* lx = (unsigned short*)lmem;   // [32][130]
        int idx = blockIdx.x - 256;
        int p = idx & 31;
        int b = idx >> 5;
        const float* xp = x + (size_t)b * CCH * 1024 + p * 32;
#pragma unroll
        for (int i = 0; i < 16; i++) {
            int ii = t + i * 256;
            int s = ii >> 5;
            int q = ii & 31;
            lx[q * 130 + s] = f2bf(xp[(size_t)s * 1024 + q]);
        }
        __syncthreads();
#pragma unroll
        for (int i = 0; i < 2; i++) {
            int tau = t + i * 256;
            int q = tau >> 4;
            int ch = tau & 15;
            const unsigned short* r = &lx[q * 130 + ch * 8];
            uint4 o;
            o.x = r[0] | ((unsigned)r[1] << 16);
            o.y = r[2] | ((unsigned)r[3] << 16);
            o.z = r[4] | ((unsigned)r[5] << 16);
            o.w = r[6] | ((unsigned)r[7] << 16);
            ((uint4*)xb16)[((((size_t)b * 32 + p) * 32) + q) * 16 + ch] = o;
        }
    }
}

// ---- conv: out[b,f,p,q] = sum_uv sum_s Wuv[f,s]*x[b,s,p+u-1,q+v-1] + cb[f] + x[b,f,p,q] -------
// Block: 2 waves = 128f x 2 rows. XCD-swizzled so each XCD serves 4 samples (A stays L2-resident).
__global__ __launch_bounds__(128) void conv_mfma(
    const float* __restrict__ x, const unsigned short* __restrict__ xb16,
    const unsigned short* __restrict__ wkt, const float* __restrict__ cb,
    float* __restrict__ out)
{
    __shared__ short8 lds8[4 * 34 * 17];      // [row][col][s-chunk], col stride 17 short8
    int t = threadIdx.x;
    int w = blockIdx.x;                       // 512 blocks
    int xcd = w & 7;
    int slot = w >> 3;
    int b = (xcd << 2) | (slot >> 4);         // wg->XCD is w%8 round-robin: XCD x owns b in [4x,4x+4)
    int p0 = (slot & 15) * 2;
    int lane = t & 63;
    int fbase = (t >> 6) * 64;
    int qcol = lane & 31;
    int klane = lane >> 5;

    {   // zero halo columns 0 and 33
        int r = t >> 5;
        int col = ((t >> 4) & 1) ? 33 : 0;
        int ch = t & 15;
        short8 zz = { 0, 0, 0, 0, 0, 0, 0, 0 };
        lds8[(r * 34 + col) * 17 + ch] = zz;
    }
    const uint4* xsrc = (const uint4*)xb16;
#pragma unroll
    for (int i = 0; i < 16; i++) {
        int tau = t + i * 128;                // 2048 uint4: rows p0-1..p0+2, cols 0..31, ch 0..15
        int ch = tau & 15;
        int q = (tau >> 4) & 31;
        int r = tau >> 9;
        int prow = p0 - 1 + r;
        uint4 v = make_uint4(0, 0, 0, 0);
        if (prow >= 0 && prow < 32)
            v = xsrc[((((size_t)b * 32 + prow) * 32) + q) * 16 + ch];
        *(uint4*)&lds8[(r * 34 + q + 1) * 17 + ch] = v;
    }
    __syncthreads();

    floatx16 acc[2][2];
#pragma unroll
    for (int mi = 0; mi < 2; mi++)
#pragma unroll
        for (int ni = 0; ni < 2; ni++)
#pragma unroll
            for (int r = 0; r < 16; r++) acc[mi][ni][r] = 0.f;

    const short8* A8 = (const short8*)wkt + ((size_t)b * 9 << 11);
#pragma unroll
    for (int v = 0; v < 3; v++)
#pragma unroll
    for (int ks = 0; ks < 8; ks++) {
        int koff = ks * 2 + klane;
        short8 br[4];
#pragma unroll
        for (int r = 0; r < 4; r++)           // B rows shared across u (u and u+1 overlap)
            br[r] = lds8[(r * 34 + qcol + v) * 17 + koff];
#pragma unroll
        for (int u = 0; u < 3; u++) {
            const short8* Au = A8 + ((size_t)(u * 3 + v) << 11);
            short8 a0 = Au[(fbase + qcol) * 16 + koff];
            short8 a1 = Au[(fbase + 32 + qcol) * 16 + koff];
            acc[0][0] = __builtin_amdgcn_mfma_f32_32x32x16_bf16(a0, br[u],     acc[0][0], 0, 0, 0);
            acc[0][1] = __builtin_amdgcn_mfma_f32_32x32x16_bf16(a0, br[u + 1], acc[0][1], 0, 0, 0);
            acc[1][0] = __builtin_amdgcn_mfma_f32_32x32x16_bf16(a1, br[u],     acc[1][0], 0, 0, 0);
            acc[1][1] = __builtin_amdgcn_mfma_f32_32x32x16_bf16(a1, br[u + 1], acc[1][1], 0, 0, 0);
        }
    }

    const size_t xb = (size_t)b * CCH * 1024;
#pragma unroll
    for (int mi = 0; mi < 2; mi++)
#pragma unroll
    for (int ni = 0; ni < 2; ni++) {
        int p = p0 + ni;
#pragma unroll
        for (int r = 0; r < 16; r++) {
            int fl = (r & 3) + 8 * (r >> 2) + 4 * klane;
            int f = fbase + mi * 32 + fl;
            size_t idx = xb + (size_t)f * 1024 + p * 32 + qcol;
            out[idx] = acc[mi][ni][r] + x[idx] + cb[f];
        }
    }
}

extern "C" void kernel_launch(void* const* d_in, const int* in_sizes, int n_in,
                              void* d_out, int out_size, void* d_ws, size_t ws_size,
                              hipStream_t stream) {
    const float* x     = (const float*)d_in[0];
    const float* z     = (const float*)d_in[1];
    const float* dw    = (const float*)d_in[2];
    const float* db    = (const float*)d_in[3];
    const float* gamma = (const float*)d_in[4];
    const float* beta  = (const float*)d_in[5];
    const float* cb    = (const float*)d_in[6];
    float* out = (float*)d_out;

    unsigned short* wkn  = (unsigned short*)d_ws;                                       // 9.44 MB
    unsigned short* wkt  = (unsigned short*)((char*)d_ws + (size_t)BSZ * NB * 2);       // 9.44 MB
    unsigned short* xb16 = (unsigned short*)((char*)d_ws + (size_t)BSZ * NB * 4);       // 8.4 MB

    hyper_gemm_bn<<<NB / 256, 256, 0, stream>>>(z, dw, db, gamma, beta, wkn);
    repack_xt<<<256 + 1024, 256, 0, stream>>>(wkn, wkt, x, xb16);
    conv_mfma<<<512, 128, 0, stream>>>(x, xb16, wkt, cb, out);
}

// Round 6
// 293.884 us; speedup vs baseline: 1.4183x; 1.4183x over previous
//
#include <hip/hip_runtime.h>

#define NB 147456   // C*C*KH*KW per sample
#define ZD 256
#define BSZ 32
#define CCH 128

typedef __attribute__((ext_vector_type(8))) short short8;
typedef __attribute__((ext_vector_type(16))) float floatx16;

__device__ __forceinline__ unsigned short f2bf(float f) {
    unsigned int u = __float_as_uint(f);
    return (unsigned short)((u + 0x7fffu + ((u >> 16) & 1u)) >> 16);
}
// pack hi16(lo),hi16(hi) -> one dword (two bf16, truncating convert)
__device__ __forceinline__ unsigned pk(unsigned hi, unsigned lo) {
    return __builtin_amdgcn_perm(hi, lo, 0x07060302u);
}

// ---- K1: h = relu(z@W+b); BN over batch; affine; bf16 Wk natural [b][n] -----------------------
// MFMA 32x32x16: M=32 batch rows in one tile. Block = 4 waves x 32 cols; 1152 blocks.
// B (dense_w) streamed fp32->bf16 (v_perm truncate), depth-2 prefetch. A (z) staged once in LDS.
__global__ __launch_bounds__(256) void hyper_mfma(
    const float* __restrict__ z, const float* __restrict__ dw,
    const float* __restrict__ db, const float* __restrict__ gamma,
    const float* __restrict__ beta, unsigned short* __restrict__ wkn)
{
    __shared__ short8 zf[16 * 64];            // A-frag per [step][lane], 16 KB
    int t = threadIdx.x;
#pragma unroll
    for (int i = 0; i < 4; i++) {             // stage z -> bf16 A-frags
        int id = t + i * 256;                 // 1024 cells
        int step = id >> 6, ln = id & 63;
        int m = ln & 31, kb = step * 16 + (ln >> 5) * 8;
        float4 w0 = *(const float4*)(z + m * 256 + kb);
        float4 w1 = *(const float4*)(z + m * 256 + kb + 4);
        uint4 u;
        u.x = pk(__float_as_uint(w0.y), __float_as_uint(w0.x));
        u.y = pk(__float_as_uint(w0.w), __float_as_uint(w0.z));
        u.z = pk(__float_as_uint(w1.y), __float_as_uint(w1.x));
        u.w = pk(__float_as_uint(w1.w), __float_as_uint(w1.z));
        zf[id] = *(short8*)&u;
    }
    __syncthreads();

    int wid = t >> 6, lane = t & 63;
    int n = blockIdx.x * 128 + wid * 32 + (lane & 31);
    int klane = lane >> 5;
    int koff = klane * 8;

    floatx16 acc;
#pragma unroll
    for (int r = 0; r < 16; r++) acc[r] = 0.f;

    unsigned ba[8], bb[8];
#define LOADB(BUF, S)                                                        \
    _Pragma("unroll") for (int j = 0; j < 8; j++)                            \
        BUF[j] = __float_as_uint(dw[(size_t)((S) * 16 + koff + j) * NB + n]);
#define DOMFMA(BUF, S)                                                       \
    {                                                                        \
        uint4 u;                                                             \
        u.x = pk(BUF[1], BUF[0]); u.y = pk(BUF[3], BUF[2]);                  \
        u.z = pk(BUF[5], BUF[4]); u.w = pk(BUF[7], BUF[6]);                  \
        acc = __builtin_amdgcn_mfma_f32_32x32x16_bf16(                       \
            zf[(S) * 64 + lane], *(short8*)&u, acc, 0, 0, 0);                \
    }
    LOADB(ba, 0)
    for (int s = 0; s < 16; s += 2) {
        LOADB(bb, s + 1)
        DOMFMA(ba, s)
        if (s + 2 < 16) LOADB(ba, s + 2)
        DOMFMA(bb, s + 1)
    }
#undef LOADB
#undef DOMFMA

    // BN epilogue: rows of the C tile are batch. lane holds 16 rows; lane^32 holds the other 16.
    float bias = db[n];
    float h[16], sp = 0.f, qp = 0.f;
#pragma unroll
    for (int r = 0; r < 16; r++) {
        float v = fmaxf(acc[r] + bias, 0.f);
        h[r] = v; sp += v; qp += v * v;
    }
    sp += __shfl_xor(sp, 32, 64);
    qp += __shfl_xor(qp, 32, 64);
    float m = sp * (1.f / 32.f);
    float var = fmaxf(qp * (1.f / 32.f) - m * m, 0.f);
    float sc = gamma[n] / (sqrtf(var) + 1e-6f);
    float bt = beta[n];
#pragma unroll
    for (int r = 0; r < 16; r++) {
        int bbrow = (r & 3) + 8 * (r >> 2) + 4 * klane;
        wkn[(size_t)bbrow * NB + n] = f2bf(sc * (h[r] - m) + bt);
    }
}

// ---- fused: blocks 0..255 repack wkn->wkt; blocks 256..1279 transpose x -> xT bf16 -----------
__global__ __launch_bounds__(256) void repack_xt(
    const unsigned short* __restrict__ wkn, unsigned short* __restrict__ wkt,
    const float* __restrict__ x, unsigned short* __restrict__ xb16)
{
    __shared__ char lmem[16 * 580 * 4];
    int t = threadIdx.x;
    if (blockIdx.x < 256) {
        unsigned int* lt = (unsigned int*)lmem;   // [16][580]
        int b = blockIdx.x >> 3;
        int s0 = (blockIdx.x & 7) * 16;
        const unsigned int* src = (const unsigned int*)wkn + ((size_t)b * NB >> 1) + (size_t)s0 * 576;
#pragma unroll
        for (int i = 0; i < 36; i++) {
            int idx = t + i * 256;
            int si = idx / 576;
            int j2 = idx - si * 576;
            lt[si * 580 + j2] = src[(size_t)si * 576 + j2];
        }
        __syncthreads();
        const unsigned short* ls = (const unsigned short*)lt;
#pragma unroll
        for (int i = 0; i < 9; i++) {
            int tau = t + i * 256;
            int half = tau & 1;
            int unit = tau >> 1;
            int uv = unit >> 7;
            int f = unit & 127;
            int col = f * 9 + uv;
            unsigned short v[8];
#pragma unroll
            for (int ss = 0; ss < 8; ss++)
                v[ss] = ls[(half * 8 + ss) * 1160 + col];
            uint4 o;
            o.x = v[0] | ((unsigned)v[1] << 16);
            o.y = v[2] | ((unsigned)v[3] << 16);
            o.z = v[4] | ((unsigned)v[5] << 16);
            o.w = v[6] | ((unsigned)v[7] << 16);
            ((uint4*)wkt)[((((size_t)b * 9 + uv) * 128 + f) * 16) + (s0 >> 3) + half] = o;
        }
    } else {
        unsigned short* lx = (unsigned short*)lmem;   // [32][130]
        int idx = blockIdx.x - 256;
        int p = idx & 31;
        int b = idx >> 5;
        const float* xp = x + (size_t)b * CCH * 1024 + p * 32;
#pragma unroll
        for (int i = 0; i < 16; i++) {
            int ii = t + i * 256;
            int s = ii >> 5;
            int q = ii & 31;
            lx[q * 130 + s] = f2bf(xp[(size_t)s * 1024 + q]);
        }
        __syncthreads();
#pragma unroll
        for (int i = 0; i < 2; i++) {
            int tau = t + i * 256;
            int q = tau >> 4;
            int ch = tau & 15;
            const unsigned short* r = &lx[q * 130 + ch * 8];
            uint4 o;
            o.x = r[0] | ((unsigned)r[1] << 16);
            o.y = r[2] | ((unsigned)r[3] << 16);
            o.z = r[4] | ((unsigned)r[5] << 16);
            o.w = r[6] | ((unsigned)r[7] << 16);
            ((uint4*)xb16)[((((size_t)b * 32 + p) * 32) + q) * 16 + ch] = o;
        }
    }
}

// ---- conv: 256 thr = 4 waves (2 f-halves x 2 row-pairs), p-tile = 4 rows, 256 blocks ----------
// Depth-1 double-buffered A prefetch (6 b128 in flight over 12 MFMAs). XCD-swizzled: 4 samples/XCD.
__global__ __launch_bounds__(256) void conv_mfma(
    const float* __restrict__ x, const unsigned short* __restrict__ xb16,
    const unsigned short* __restrict__ wkt, const float* __restrict__ cb,
    float* __restrict__ out)
{
    __shared__ short8 lds8[6 * 34 * 17];      // 55.5 KB: rows p0-1..p0+4, col stride 17 chunks
    int t = threadIdx.x;
    int w = blockIdx.x;                       // 256 blocks
    int xcd = w & 7, slot = w >> 3;
    int b = (xcd << 2) | (slot & 3);          // 4 samples per XCD -> Wk slice L2-resident
    int p0 = (slot >> 2) * 4;
    int wid = t >> 6, lane = t & 63;
    int fbase = (wid & 1) * 64;
    int rbase = (wid >> 1) * 2;               // this wave's row-pair offset in the LDS window
    int qcol = lane & 31, klane = lane >> 5;

    if (t < 192) {                            // zero halo cols 0 and 33, 6 rows
        int r = t >> 5;
        int col = ((t >> 4) & 1) ? 33 : 0;
        int ch = t & 15;
        short8 zz = { 0, 0, 0, 0, 0, 0, 0, 0 };
        lds8[(r * 34 + col) * 17 + ch] = zz;
    }
    const uint4* xsrc = (const uint4*)xb16;
#pragma unroll
    for (int i = 0; i < 12; i++) {            // stage 6 rows x 32 q x 16 ch = 3072 uint4
        int tau = t + i * 256;
        int ch = tau & 15;
        int q = (tau >> 4) & 31;
        int r = tau >> 9;                     // 0..5
        int prow = p0 - 1 + r;
        uint4 v = make_uint4(0, 0, 0, 0);
        if (prow >= 0 && prow < 32)
            v = xsrc[((((size_t)b * 32 + prow) * 32) + q) * 16 + ch];
        *(uint4*)&lds8[(r * 34 + q + 1) * 17 + ch] = v;
    }
    __syncthreads();

    floatx16 acc[2][2];
#pragma unroll
    for (int mi = 0; mi < 2; mi++)
#pragma unroll
        for (int ni = 0; ni < 2; ni++)
#pragma unroll
            for (int r = 0; r < 16; r++) acc[mi][ni][r] = 0.f;

    const short8* A8 = (const short8*)wkt + ((size_t)b * 9 << 11);
    short8 Abuf0[6], Abuf1[6];

#define LOAD6(BUF, ST)                                                        \
    {                                                                         \
        int v_ = (ST) >> 3, ks_ = (ST) & 7;                                   \
        int ko_ = ks_ * 2 + klane;                                            \
        _Pragma("unroll") for (int u_ = 0; u_ < 3; u_++) {                    \
            const short8* Au_ = A8 + ((size_t)(u_ * 3 + v_) << 11);           \
            BUF[u_ * 2]     = Au_[(fbase + qcol) * 16 + ko_];                 \
            BUF[u_ * 2 + 1] = Au_[(fbase + 32 + qcol) * 16 + ko_];            \
        }                                                                     \
    }
#define COMPUTE(BUF, ST)                                                      \
    {                                                                         \
        int v_ = (ST) >> 3, ks_ = (ST) & 7;                                   \
        int ko_ = ks_ * 2 + klane;                                            \
        short8 br[4];                                                         \
        _Pragma("unroll") for (int r_ = 0; r_ < 4; r_++)                      \
            br[r_] = lds8[((rbase + r_) * 34 + qcol + v_) * 17 + ko_];        \
        _Pragma("unroll") for (int u_ = 0; u_ < 3; u_++) {                    \
            acc[0][0] = __builtin_amdgcn_mfma_f32_32x32x16_bf16(              \
                BUF[u_ * 2], br[u_], acc[0][0], 0, 0, 0);                     \
            acc[0][1] = __builtin_amdgcn_mfma_f32_32x32x16_bf16(              \
                BUF[u_ * 2], br[u_ + 1], acc[0][1], 0, 0, 0);                 \
            acc[1][0] = __builtin_amdgcn_mfma_f32_32x32x16_bf16(              \
                BUF[u_ * 2 + 1], br[u_], acc[1][0], 0, 0, 0);                 \
            acc[1][1] = __builtin_amdgcn_mfma_f32_32x32x16_bf16(              \
                BUF[u_ * 2 + 1], br[u_ + 1], acc[1][1], 0, 0, 0);             \
        }                                                                     \
    }

    LOAD6(Abuf0, 0)
    for (int st = 0; st < 24; st += 2) {
        LOAD6(Abuf1, st + 1)
        COMPUTE(Abuf0, st)
        if (st + 2 < 24) LOAD6(Abuf0, st + 2)
        COMPUTE(Abuf1, st + 1)
    }
#undef LOAD6
#undef COMPUTE

    const size_t xb = (size_t)b * CCH * 1024;
    int prow0 = p0 + rbase;
#pragma unroll
    for (int mi = 0; mi < 2; mi++)
#pragma unroll
    for (int ni = 0; ni < 2; ni++) {
        int p = prow0 + ni;
#pragma unroll
        for (int r = 0; r < 16; r++) {
            int fl = (r & 3) + 8 * (r >> 2) + 4 * klane;
            int f = fbase + mi * 32 + fl;
            size_t idx = xb + (size_t)f * 1024 + p * 32 + qcol;
            out[idx] = acc[mi][ni][r] + x[idx] + cb[f];
        }
    }
}

extern "C" void kernel_launch(void* const* d_in, const int* in_sizes, int n_in,
                              void* d_out, int out_size, void* d_ws, size_t ws_size,
                              hipStream_t stream) {
    const float* x     = (const float*)d_in[0];
    const float* z     = (const float*)d_in[1];
    const float* dw    = (const float*)d_in[2];
    const float* db    = (const float*)d_in[3];
    const float* gamma = (const float*)d_in[4];
    const float* beta  = (const float*)d_in[5];
    const float* cb    = (const float*)d_in[6];
    float* out = (float*)d_out;

    unsigned short* wkn  = (unsigned short*)d_ws;                                       // 9.44 MB
    unsigned short* wkt  = (unsigned short*)((char*)d_ws + (size_t)BSZ * NB * 2);       // 9.44 MB
    unsigned short* xb16 = (unsigned short*)((char*)d_ws + (size_t)BSZ * NB * 4);       // 8.4 MB

    hyper_mfma<<<NB / 128, 256, 0, stream>>>(z, dw, db, gamma, beta, wkn);
    repack_xt<<<256 + 1024, 256, 0, stream>>>(wkn, wkt, x, xb16);
    conv_mfma<<<256, 256, 0, stream>>>(x, xb16, wkt, cb, out);
}